// Round 6
// baseline (447.961 us; speedup 1.0000x reference)
//
#include <hip/hip_runtime.h>
#include <hip/hip_bf16.h>
#include <cstdint>

#define N_ATOMS 100000
#define NFEAT   256
#define NMOL    1024
#define RSLABS  1564    // 100096 / 64 rows per block

static constexpr float SCALE_C = 5.992277830325989f;
static constexpr float SHIFT_C = -406274.63784969115f;

typedef __attribute__((ext_vector_type(8))) short short8;    // bf16x8 MFMA operand
typedef __attribute__((ext_vector_type(4))) float float4_t;  // f32x4 accumulator

__device__ __forceinline__ unsigned short f2bf(float x) {
    union { float f; uint32_t u; } v; v.f = x;
    uint32_t r = (v.u + 0x7fffu + ((v.u >> 16) & 1u)) >> 16;
    return (unsigned short)r;
}

// pack two fp32 -> two bf16 (round-half-up) in one v_perm
__device__ __forceinline__ uint32_t pk(float lo, float hi) {
    union { float f; uint32_t u; } a, b; a.f = lo; b.f = hi;
    return __builtin_amdgcn_perm(b.u + 0x8000u, a.u + 0x8000u, 0x07060302u);
}

__device__ __forceinline__ float silu(float x) {
    return x / (1.0f + __expf(-x));
}

// async global->LDS, 16B/lane; LDS dest wave-uniform, lane i lands at +i*16B
__device__ __forceinline__ void async16(void* lds, const void* g) {
    __builtin_amdgcn_global_load_lds(
        (const __attribute__((address_space(1))) unsigned int*)(uintptr_t)g,
        (__attribute__((address_space(3))) unsigned int*)(uint32_t)(uintptr_t)lds,
        16, 0, 0);
}

// W image (prep output; shorts): pos = (k>>7)*32768 + n*128 +
//   (((k>>3)&15 ^ (n&15))<<3) + (k&7).   [R2-R4: 0 bank conflicts]
// A block's 64-col tile = 2 planes x 8192 shorts, each contiguous.
// Tile-local fragment read (n in 0..63, kc in 0..31):
__device__ __forceinline__ short8 wfrag(const unsigned short* Ws, int n, int kc) {
    return *(const short8*)&Ws[((kc >> 4) << 13) + n * 128 +
                               ((((kc & 15) ^ (n & 15)) & 15) << 3)];
}

// ---------------------------------------------------------------------------
// Prep: W1,W2 fp32 [k][n] -> bf16 swizzled plane images; init out[] = SHIFT.
// ---------------------------------------------------------------------------
__global__ void prep(const float* __restrict__ W1, const float* __restrict__ W2,
                     unsigned short* __restrict__ W1i, unsigned short* __restrict__ W2i,
                     float* __restrict__ out) {
    int g = blockIdx.x * 256 + threadIdx.x;          // 0 .. 131071
    const float* W = (g < 65536) ? W1 : W2;
    unsigned short* Wi = (g < 65536) ? W1i : W2i;
    int idx = g & 65535;
    int k = idx >> 8, n = idx & 255;
    int kc = (k >> 3) & 15;
    int pos = ((k >> 7) << 15) + n * 128 + (((kc ^ (n & 15)) & 15) << 3) + (k & 7);
    Wi[pos] = f2bf(W[idx]);
    if (g < NMOL) out[g] = SHIFT_C;
}

// stage this block's 64-col W tile (32 KB) into Ws; one barrier after.
__device__ __forceinline__ void stage_w(unsigned short* Ws,
                                        const unsigned short* __restrict__ Wimg,
                                        int c0, int w, int lane) {
#pragma unroll
    for (int i = 0; i < 8; ++i) {
        int t = w * 8 + i;                       // 0..31 KB-chunks
        const unsigned short* src = Wimg + ((t >> 4) << 15) + c0 * 128 +
                                    ((t & 15) << 9) + lane * 8;
        async16(&Ws[t << 9], src);
    }
}

// ---------------------------------------------------------------------------
// Layer 1: H1 = silu(A @ W1 + b1).  Block: 64 atoms x 64 cols, 4 waves
// (wave = 16 atoms x 64 cols), K=256 unrolled, W-tile in LDS staged once.
// A: fp32 global->VGPR, inline bf16 convert. Swapped MFMA operands so each
// lane's acc holds 4 consecutive H1 cols of its own atom -> 8B stores.
// ---------------------------------------------------------------------------
__global__ __launch_bounds__(256, 4)
void gemm1(const float* __restrict__ A, const unsigned short* __restrict__ Wimg,
           const float* __restrict__ b1, unsigned short* __restrict__ H1) {
    __shared__ unsigned short Ws[16384];   // 32 KB

    const int tid = threadIdx.x;
    const int w = tid >> 6, lane = tid & 63;
    const int fl = lane & 15, qd = lane >> 4;
    const int c0 = blockIdx.y * 64;

    stage_w(Ws, Wimg, c0, w, lane);
    __syncthreads();

    const int row = blockIdx.x * 64 + w * 16 + fl;   // this lane's atom
    const bool valid = row < N_ATOMS;
    const float* ap = A + (size_t)row * 256 + qd * 8;

    float4_t acc[4] = {};   // acc[nt]: cols c0 + nt*16 + qd*4 + r, atom=row
#pragma unroll
    for (int s = 0; s < 8; ++s) {
        float4 v0 = {0.f, 0.f, 0.f, 0.f}, v1 = {0.f, 0.f, 0.f, 0.f};
        if (valid) {
            v0 = *(const float4*)(ap + s * 32);
            v1 = *(const float4*)(ap + s * 32 + 4);
        }
        union { uint32_t u4[4]; short8 s8; } cv;
        cv.u4[0] = pk(v0.x, v0.y); cv.u4[1] = pk(v0.z, v0.w);
        cv.u4[2] = pk(v1.x, v1.y); cv.u4[3] = pk(v1.z, v1.w);
        const int kc = s * 4 + qd;
#pragma unroll
        for (int nt = 0; nt < 4; ++nt) {
            short8 wf = wfrag(Ws, nt * 16 + fl, kc);
            acc[nt] = __builtin_amdgcn_mfma_f32_16x16x32_bf16(wf, cv.s8, acc[nt], 0, 0, 0);
        }
    }

    if (valid) {
#pragma unroll
        for (int nt = 0; nt < 4; ++nt) {
            int nb = c0 + nt * 16 + qd * 4;
            float4 b4 = *(const float4*)&b1[nb];
            uint2 o;
            o.x = pk(silu(acc[nt][0] + b4.x), silu(acc[nt][1] + b4.y));
            o.y = pk(silu(acc[nt][2] + b4.z), silu(acc[nt][3] + b4.w));
            *(uint2*)&H1[(size_t)row * 256 + nb] = o;
        }
    }
}

// ---------------------------------------------------------------------------
// Layer 2+3+pool: out[mol] += SCALE*(silu(H1@W2+b2).W3 + b3). Same tile
// shape, natural operand order. Epilogue: silu, dot W3 over this chunk's 64
// cols, fl-butterfly reduce, one atomicAdd per atom per col-chunk.
// ---------------------------------------------------------------------------
__global__ __launch_bounds__(256, 4)
void gemm2(const unsigned short* __restrict__ H1, const unsigned short* __restrict__ Wimg,
           const float* __restrict__ b2, const float* __restrict__ W3,
           const float* __restrict__ b3, const int* __restrict__ batch,
           float* __restrict__ out) {
    __shared__ unsigned short Ws[16384];   // 32 KB

    const int tid = threadIdx.x;
    const int w = tid >> 6, lane = tid & 63;
    const int fl = lane & 15, qd = lane >> 4;
    const int c0 = blockIdx.y * 64;

    stage_w(Ws, Wimg, c0, w, lane);
    __syncthreads();

    const int rbase = blockIdx.x * 64 + w * 16;
    const int lrow = rbase + fl;                 // lane's H1 row for a-frags
    const bool lvalid = lrow < N_ATOMS;
    const unsigned short* hp = H1 + (size_t)lrow * 256 + qd * 8;

    float4_t acc[4] = {};   // acc[nt]: atom = rbase + qd*4 + r, col = c0+nt*16+fl
#pragma unroll
    for (int s = 0; s < 8; ++s) {
        short8 hf = (short8){0, 0, 0, 0, 0, 0, 0, 0};
        if (lvalid) hf = *(const short8*)(hp + s * 32);
        const int kc = s * 4 + qd;
#pragma unroll
        for (int nt = 0; nt < 4; ++nt) {
            short8 wf = wfrag(Ws, nt * 16 + fl, kc);
            acc[nt] = __builtin_amdgcn_mfma_f32_16x16x32_bf16(hf, wf, acc[nt], 0, 0, 0);
        }
    }

    // per-lane partial energies for 4 atoms (rows qd*4+r) over cols c0+nt*16+fl
    float rs[4] = {};
#pragma unroll
    for (int nt = 0; nt < 4; ++nt) {
        int col = c0 + nt * 16 + fl;
        float bb = b2[col];
        float w3 = W3[col];
#pragma unroll
        for (int r = 0; r < 4; ++r)
            rs[r] += silu(acc[nt][r] + bb) * w3;
    }
#pragma unroll
    for (int r = 0; r < 4; ++r) {
        float v = rs[r];
        v += __shfl_xor(v, 1);
        v += __shfl_xor(v, 2);
        v += __shfl_xor(v, 4);
        v += __shfl_xor(v, 8);
        rs[r] = v;
    }
    const float badd = (blockIdx.y == 0) ? b3[0] : 0.0f;
    if (fl == 0) {
#pragma unroll
        for (int r = 0; r < 4; ++r) {
            int atom = rbase + qd * 4 + r;
            if (atom < N_ATOMS)
                atomicAdd(&out[batch[atom]], (rs[r] + badd) * SCALE_C);
        }
    }
}

// ---------------------------------------------------------------------------
extern "C" void kernel_launch(void* const* d_in, const int* in_sizes, int n_in,
                              void* d_out, int out_size, void* d_ws, size_t ws_size,
                              hipStream_t stream) {
    const float* A     = (const float*)d_in[0];
    const int*   batch = (const int*)d_in[1];
    const float* W1    = (const float*)d_in[2];
    const float* b1    = (const float*)d_in[3];
    const float* W2    = (const float*)d_in[4];
    const float* b2    = (const float*)d_in[5];
    const float* W3    = (const float*)d_in[6];
    const float* b3    = (const float*)d_in[7];
    float* out = (float*)d_out;

    unsigned short* H1  = (unsigned short*)d_ws;            // 100096*256 bf16
    unsigned short* W1i = H1 + (size_t)100096 * NFEAT;      // 65536 shorts
    unsigned short* W2i = W1i + 65536;                      // 65536 shorts

    prep<<<dim3(512), 256, 0, stream>>>(W1, W2, W1i, W2i, out);
    gemm1<<<dim3(RSLABS, 4), 256, 0, stream>>>(A, W1i, b1, H1);
    gemm2<<<dim3(RSLABS, 4), 256, 0, stream>>>(H1, W2i, b2, W3, b3, batch, out);
}

// Round 7
// 389.246 us; speedup vs baseline: 1.1508x; 1.1508x over previous
//
#include <hip/hip_runtime.h>
#include <hip/hip_bf16.h>
#include <cstdint>

#define N_ATOMS 100000
#define NFEAT   256
#define NMOL    1024
#define NSLABS  391     // ceil(100096/256) slabs of 256 atoms
#define NBLKS   (NSLABS * 4)   // x4 col-chunks of 64

static constexpr float SCALE_C = 5.992277830325989f;
static constexpr float SHIFT_C = -406274.63784969115f;

typedef __attribute__((ext_vector_type(8))) short short8;    // bf16x8 MFMA operand
typedef __attribute__((ext_vector_type(4))) float float4_t;  // f32x4 accumulator

__device__ __forceinline__ unsigned short f2bf(float x) {
    union { float f; uint32_t u; } v; v.f = x;
    uint32_t r = (v.u + 0x7fffu + ((v.u >> 16) & 1u)) >> 16;
    return (unsigned short)r;
}

// pack two fp32 -> two bf16 (round-half-up) in one v_perm
__device__ __forceinline__ uint32_t pk(float lo, float hi) {
    union { float f; uint32_t u; } a, b; a.f = lo; b.f = hi;
    return __builtin_amdgcn_perm(b.u + 0x8000u, a.u + 0x8000u, 0x07060302u);
}

__device__ __forceinline__ float silu(float x) {
    return x / (1.0f + __expf(-x));
}

// async global->LDS, 16B/lane; LDS dest wave-uniform, lane i lands at +i*16B
__device__ __forceinline__ void async16(void* lds, const void* g) {
    __builtin_amdgcn_global_load_lds(
        (const __attribute__((address_space(1))) unsigned int*)(uintptr_t)g,
        (__attribute__((address_space(3))) unsigned int*)(uint32_t)(uintptr_t)lds,
        16, 0, 0);
}

// W image (prep output; shorts): pos = (k>>7)*32768 + n*128 +
//   (((k>>3)&15 ^ (n&15))<<3) + (k&7).   [R2-R6: verified, 0 bank conflicts]
// Tile-local fragment read (n in 0..63, kc in 0..31):
__device__ __forceinline__ short8 wfrag(const unsigned short* Ws, int n, int kc) {
    return *(const short8*)&Ws[((kc >> 4) << 13) + n * 128 +
                               ((((kc & 15) ^ (n & 15)) & 15) << 3)];
}

// ---------------------------------------------------------------------------
// Prep: W1,W2 fp32 [k][n] -> bf16 swizzled plane images; init out[] = SHIFT.
// ---------------------------------------------------------------------------
__global__ void prep(const float* __restrict__ W1, const float* __restrict__ W2,
                     unsigned short* __restrict__ W1i, unsigned short* __restrict__ W2i,
                     float* __restrict__ out) {
    int g = blockIdx.x * 256 + threadIdx.x;          // 0 .. 131071
    const float* W = (g < 65536) ? W1 : W2;
    unsigned short* Wi = (g < 65536) ? W1i : W2i;
    int idx = g & 65535;
    int k = idx >> 8, n = idx & 255;
    int kc = (k >> 3) & 15;
    int pos = ((k >> 7) << 15) + n * 128 + (((kc ^ (n & 15)) & 15) << 3) + (k & 7);
    Wi[pos] = f2bf(W[idx]);
    if (g < NMOL) out[g] = SHIFT_C;
}

// stage this block's 64-col W tile (32 KB) into Ws [R6-verified]
__device__ __forceinline__ void stage_w(unsigned short* Ws,
                                        const unsigned short* __restrict__ Wimg,
                                        int c0, int w, int lane) {
#pragma unroll
    for (int i = 0; i < 8; ++i) {
        int t = w * 8 + i;                       // 0..31 KB-chunks
        const unsigned short* src = Wimg + ((t >> 4) << 15) + c0 * 128 +
                                    ((t & 15) << 9) + lane * 8;
        async16(&Ws[t << 9], src);
    }
}

// ---------------------------------------------------------------------------
// Layer 1: H1 = silu(A @ W1 + b1). Block = 256-atom slab x 64 cols; W-tile
// staged to LDS once, then 4 chunk-iterations of 64 atoms with NO further
// barriers. All 16 A-loads hoisted per chunk (vmcnt-pipelined). Swapped MFMA
// operands so each lane's acc holds 4 consecutive H1 cols of its atom.
// ---------------------------------------------------------------------------
__global__ __launch_bounds__(256, 4)
void gemm1(const float* __restrict__ A, const unsigned short* __restrict__ Wimg,
           const float* __restrict__ b1, unsigned short* __restrict__ H1) {
    __shared__ unsigned short Ws[16384];   // 32 KB

    const int tid = threadIdx.x;
    const int w = tid >> 6, lane = tid & 63;
    const int fl = lane & 15, qd = lane >> 4;
    const int slab = blockIdx.x >> 2;
    const int c0 = (blockIdx.x & 3) * 64;

    stage_w(Ws, Wimg, c0, w, lane);
    __syncthreads();

    // per-lane bias for its 4 output cols per nt (invariant across chunks)
    float4 b4[4];
#pragma unroll
    for (int nt = 0; nt < 4; ++nt)
        b4[nt] = *(const float4*)&b1[c0 + nt * 16 + qd * 4];

    for (int chunk = 0; chunk < 4; ++chunk) {
        const int row = slab * 256 + chunk * 64 + w * 16 + fl;
        const bool valid = row < N_ATOMS;
        const float* ap = A + (size_t)row * 256 + qd * 8;

        // hoist all 16 dwordx4 loads for this chunk
        float4 va[8][2];
#pragma unroll
        for (int s = 0; s < 8; ++s) {
            if (valid) {
                va[s][0] = *(const float4*)(ap + s * 32);
                va[s][1] = *(const float4*)(ap + s * 32 + 4);
            } else {
                va[s][0] = make_float4(0.f, 0.f, 0.f, 0.f);
                va[s][1] = make_float4(0.f, 0.f, 0.f, 0.f);
            }
        }

        float4_t acc[4] = {};
#pragma unroll
        for (int s = 0; s < 8; ++s) {
            union { uint32_t u4[4]; short8 s8; } cv;
            cv.u4[0] = pk(va[s][0].x, va[s][0].y);
            cv.u4[1] = pk(va[s][0].z, va[s][0].w);
            cv.u4[2] = pk(va[s][1].x, va[s][1].y);
            cv.u4[3] = pk(va[s][1].z, va[s][1].w);
            const int kc = s * 4 + qd;
#pragma unroll
            for (int nt = 0; nt < 4; ++nt) {
                short8 wf = wfrag(Ws, nt * 16 + fl, kc);
                acc[nt] = __builtin_amdgcn_mfma_f32_16x16x32_bf16(wf, cv.s8, acc[nt], 0, 0, 0);
            }
        }

        if (valid) {
#pragma unroll
            for (int nt = 0; nt < 4; ++nt) {
                int nb = c0 + nt * 16 + qd * 4;
                uint2 o;
                o.x = pk(silu(acc[nt][0] + b4[nt].x), silu(acc[nt][1] + b4[nt].y));
                o.y = pk(silu(acc[nt][2] + b4[nt].z), silu(acc[nt][3] + b4[nt].w));
                *(uint2*)&H1[(size_t)row * 256 + nb] = o;
            }
        }
    }
}

// ---------------------------------------------------------------------------
// Layer 2+3+pool. Same slab structure. Pooling: sorted-batch block-local
// segment reduction into LDS bucket[1024] (ds_add_f32), then <=1024 scans
// with one global atomic per NONZERO bucket (~3-8 per block, not 256).
// ---------------------------------------------------------------------------
__global__ __launch_bounds__(256, 4)
void gemm2(const unsigned short* __restrict__ H1, const unsigned short* __restrict__ Wimg,
           const float* __restrict__ b2, const float* __restrict__ W3,
           const float* __restrict__ b3, const int* __restrict__ batch,
           float* __restrict__ out) {
    __shared__ unsigned short Ws[16384];   // 32 KB
    __shared__ float bucket[NMOL];         // 4 KB

    const int tid = threadIdx.x;
    const int w = tid >> 6, lane = tid & 63;
    const int fl = lane & 15, qd = lane >> 4;
    const int slab = blockIdx.x >> 2;
    const int yc = blockIdx.x & 3;
    const int c0 = yc * 64;

    stage_w(Ws, Wimg, c0, w, lane);
#pragma unroll
    for (int i = 0; i < 4; ++i) bucket[tid + i * 256] = 0.0f;
    __syncthreads();

    const float b3v = (yc == 0) ? b3[0] : 0.0f;
    float bbv[4], w3v[4];
#pragma unroll
    for (int nt = 0; nt < 4; ++nt) {
        bbv[nt] = b2[c0 + nt * 16 + fl];
        w3v[nt] = W3[c0 + nt * 16 + fl];
    }

    for (int chunk = 0; chunk < 4; ++chunk) {
        const int base = slab * 256 + chunk * 64;
        const int lrow = base + w * 16 + fl;
        const bool lvalid = lrow < N_ATOMS;
        const unsigned short* hp = H1 + (size_t)lrow * 256 + qd * 8;

        // hoist the 8 short8 H1 loads
        short8 hf[8];
#pragma unroll
        for (int s = 0; s < 8; ++s) {
            if (lvalid) hf[s] = *(const short8*)(hp + s * 32);
            else        hf[s] = (short8){0, 0, 0, 0, 0, 0, 0, 0};
        }

        float4_t acc[4] = {};
#pragma unroll
        for (int s = 0; s < 8; ++s) {
            const int kc = s * 4 + qd;
#pragma unroll
            for (int nt = 0; nt < 4; ++nt) {
                short8 wf = wfrag(Ws, nt * 16 + fl, kc);
                acc[nt] = __builtin_amdgcn_mfma_f32_16x16x32_bf16(hf[s], wf, acc[nt], 0, 0, 0);
            }
        }

        // per-lane partials for atoms base + w*16 + qd*4 + r over 64 cols
        float rs[4] = {};
#pragma unroll
        for (int nt = 0; nt < 4; ++nt)
#pragma unroll
            for (int r = 0; r < 4; ++r)
                rs[r] += silu(acc[nt][r] + bbv[nt]) * w3v[nt];
#pragma unroll
        for (int r = 0; r < 4; ++r) {
            float v = rs[r];
            v += __shfl_xor(v, 1);
            v += __shfl_xor(v, 2);
            v += __shfl_xor(v, 4);
            v += __shfl_xor(v, 8);
            rs[r] = v;
        }
        // lanes fl==0 own 4 consecutive atoms each; sorted batch -> usually
        // one molecule; LDS segment-accumulate
        if (fl == 0) {
            int atom0 = base + w * 16 + qd * 4;
            if (atom0 < N_ATOMS) {   // atom0 % 4 == 0, so all 4 rows valid
                int4 mb = *(const int4*)&batch[atom0];
                float v0 = rs[0] + b3v, v1 = rs[1] + b3v,
                      v2 = rs[2] + b3v, v3 = rs[3] + b3v;
                if (mb.x == mb.w) {
                    atomicAdd(&bucket[mb.x], ((v0 + v1) + (v2 + v3)));
                } else {
                    atomicAdd(&bucket[mb.x], v0);
                    atomicAdd(&bucket[mb.y], v1);
                    atomicAdd(&bucket[mb.z], v2);
                    atomicAdd(&bucket[mb.w], v3);
                }
            }
        }
    }
    __syncthreads();
#pragma unroll
    for (int i = 0; i < 4; ++i) {
        int m = tid + i * 256;
        float v = bucket[m];
        if (v != 0.0f) atomicAdd(&out[m], v * SCALE_C);
    }
}

// ---------------------------------------------------------------------------
extern "C" void kernel_launch(void* const* d_in, const int* in_sizes, int n_in,
                              void* d_out, int out_size, void* d_ws, size_t ws_size,
                              hipStream_t stream) {
    const float* A     = (const float*)d_in[0];
    const int*   batch = (const int*)d_in[1];
    const float* W1    = (const float*)d_in[2];
    const float* b1    = (const float*)d_in[3];
    const float* W2    = (const float*)d_in[4];
    const float* b2    = (const float*)d_in[5];
    const float* W3    = (const float*)d_in[6];
    const float* b3    = (const float*)d_in[7];
    float* out = (float*)d_out;

    unsigned short* H1  = (unsigned short*)d_ws;            // 100096*256 bf16
    unsigned short* W1i = H1 + (size_t)100096 * NFEAT;      // 65536 shorts
    unsigned short* W2i = W1i + 65536;                      // 65536 shorts

    prep<<<dim3(512), 256, 0, stream>>>(W1, W2, W1i, W2i, out);
    gemm1<<<dim3(NBLKS), 256, 0, stream>>>(A, W1i, b1, H1);
    gemm2<<<dim3(NBLKS), 256, 0, stream>>>(H1, W2i, b2, W3, b3, batch, out);
}

// Round 8
// 211.152 us; speedup vs baseline: 2.1215x; 1.8434x over previous
//
#include <hip/hip_runtime.h>
#include <hip/hip_bf16.h>
#include <cstdint>

#define N_ATOMS 100000
#define NFEAT   256
#define NMOL    1024
#define NU      6256    // 100096 / 16 atoms per unit

static constexpr float SCALE_C = 5.992277830325989f;
static constexpr float SHIFT_C = -406274.63784969115f;

typedef __attribute__((ext_vector_type(8))) short short8;    // bf16x8 MFMA operand
typedef __attribute__((ext_vector_type(4))) float float4_t;  // f32x4 accumulator

__device__ __forceinline__ unsigned short f2bf(float x) {
    union { float f; uint32_t u; } v; v.f = x;
    uint32_t r = (v.u + 0x7fffu + ((v.u >> 16) & 1u)) >> 16;
    return (unsigned short)r;
}

// pack two fp32 -> two bf16 (round-half-up) in one v_perm
__device__ __forceinline__ uint32_t pk(float lo, float hi) {
    union { float f; uint32_t u; } a, b; a.f = lo; b.f = hi;
    return __builtin_amdgcn_perm(b.u + 0x8000u, a.u + 0x8000u, 0x07060302u);
}

__device__ __forceinline__ float silu(float x) {
    return x / (1.0f + __expf(-x));
}

// async global->LDS, 16B/lane; LDS dest wave-uniform, lane i lands at +i*16B
__device__ __forceinline__ void async16(void* lds, const void* g) {
    __builtin_amdgcn_global_load_lds(
        (const __attribute__((address_space(1))) unsigned int*)(uintptr_t)g,
        (__attribute__((address_space(3))) unsigned int*)(uint32_t)(uintptr_t)lds,
        16, 0, 0);
}

// Full 256x256 W image in LDS (R4-verified layout, 0 bank conflicts):
//   pos = (kc>>4)*32768 + n*128 + (((kc&15) ^ (n&15))<<3)  [+ (k&7)]
__device__ __forceinline__ short8 wfrag(const unsigned short* Wlds, int n, int kc) {
    return *(const short8*)&Wlds[((kc >> 4) << 15) + n * 128 +
                                 ((((kc & 15) ^ (n & 15)) & 15) << 3)];
}

// ---------------------------------------------------------------------------
// Prep: W1,W2 fp32 [k][n] -> bf16 swizzled plane images; init out[] = SHIFT.
// ---------------------------------------------------------------------------
__global__ void prep(const float* __restrict__ W1, const float* __restrict__ W2,
                     unsigned short* __restrict__ W1i, unsigned short* __restrict__ W2i,
                     float* __restrict__ out) {
    int g = blockIdx.x * 256 + threadIdx.x;          // 0 .. 131071
    const float* W = (g < 65536) ? W1 : W2;
    unsigned short* Wi = (g < 65536) ? W1i : W2i;
    int idx = g & 65535;
    int k = idx >> 8, n = idx & 255;
    int kc = (k >> 3) & 15;
    int pos = ((k >> 7) << 15) + n * 128 + (((kc ^ (n & 15)) & 15) << 3) + (k & 7);
    Wi[pos] = f2bf(W[idx]);
    if (g < NMOL) out[g] = SHIFT_C;
}

// ---------------------------------------------------------------------------
// Layer 1: H1 = silu(A @ W1 + b1). 512 thr = 8 waves, 1 block/CU; full W1
// (128 KB) staged to LDS once, ONE barrier total. Waves stream 16-atom x
// 256-col units via per-block LDS steal counter; A loads prefetched one
// k-step ahead (depth-2 pipeline). acc[16]=64 regs -> no spill. Swapped MFMA
// operands: lane fl owns atom u*16+fl, cols j*16+qd*4+r -> uint2 stores.
// ---------------------------------------------------------------------------
__global__ __launch_bounds__(512, 2)
void gemm1(const float* __restrict__ A, const unsigned short* __restrict__ Wimg,
           const float* __restrict__ b1, unsigned short* __restrict__ H1) {
    __shared__ unsigned short Wlds[65536];   // 128 KB
    __shared__ float b1L[256];
    __shared__ int uctr;

    const int tid = threadIdx.x;
    const int w = tid >> 6, lane = tid & 63;
    const int fl = lane & 15, qd = lane >> 4;

#pragma unroll
    for (int i = 0; i < 16; ++i)
        async16(&Wlds[(w * 16 + i) * 512], Wimg + (w * 16 + i) * 512 + lane * 8);
    if (tid < 64) ((float4*)b1L)[tid] = ((const float4*)b1)[tid];
    if (tid == 0) uctr = 0;
    __syncthreads();

    for (;;) {
        int t = 0;
        if (lane == 0) t = atomicAdd(&uctr, 1);   // LDS atomic
        t = __shfl(t, 0);
        const int u = blockIdx.x + (t << 8);      // stride-256 across blocks
        if (u >= NU) break;

        const int row = u * 16 + fl;              // this lane's atom
        const bool valid = row < N_ATOMS;
        const float* ap = A + (size_t)row * 256 + qd * 8;

        float4 c0, c1;
        if (valid) { c0 = *(const float4*)ap; c1 = *(const float4*)(ap + 4); }
        else       { c0 = make_float4(0, 0, 0, 0); c1 = c0; }

        float4_t acc[16] = {};
#pragma unroll
        for (int s = 0; s < 8; ++s) {
            float4 n0 = make_float4(0, 0, 0, 0), n1 = n0;
            if (s < 7 && valid) {                  // prefetch next k-step
                n0 = *(const float4*)(ap + (s + 1) * 32);
                n1 = *(const float4*)(ap + (s + 1) * 32 + 4);
            }
            union { uint32_t u4[4]; short8 s8; } cv;
            cv.u4[0] = pk(c0.x, c0.y); cv.u4[1] = pk(c0.z, c0.w);
            cv.u4[2] = pk(c1.x, c1.y); cv.u4[3] = pk(c1.z, c1.w);
            const int kc = s * 4 + qd;
#pragma unroll
            for (int j = 0; j < 16; ++j) {
                short8 wf = wfrag(Wlds, j * 16 + fl, kc);
                acc[j] = __builtin_amdgcn_mfma_f32_16x16x32_bf16(wf, cv.s8, acc[j], 0, 0, 0);
            }
            c0 = n0; c1 = n1;
        }

        if (valid) {
#pragma unroll
            for (int j = 0; j < 16; ++j) {
                int nb = j * 16 + qd * 4;
                float4 b4 = *(const float4*)&b1L[nb];
                uint2 o;
                o.x = pk(silu(acc[j][0] + b4.x), silu(acc[j][1] + b4.y));
                o.y = pk(silu(acc[j][2] + b4.z), silu(acc[j][3] + b4.w));
                *(uint2*)&H1[(size_t)row * 256 + nb] = o;
            }
        }
    }
}

// ---------------------------------------------------------------------------
// Layer 2+3+pool: out[mol] += SCALE*(silu(H1@W2+b2).W3 + b3). Same streaming
// structure, natural operand order; unit covers ALL 256 cols so b3 is added
// once per atom. Pooling via LDS bucket[1024] (R7-verified), one global
// atomic per nonzero bucket at the end.
// ---------------------------------------------------------------------------
__global__ __launch_bounds__(512, 2)
void gemm2(const unsigned short* __restrict__ H1, const unsigned short* __restrict__ Wimg,
           const float* __restrict__ b2, const float* __restrict__ W3,
           const float* __restrict__ b3, const int* __restrict__ batch,
           float* __restrict__ out) {
    __shared__ unsigned short Wlds[65536];   // 128 KB
    __shared__ float bucket[NMOL];           // 4 KB
    __shared__ int uctr;

    const int tid = threadIdx.x;
    const int w = tid >> 6, lane = tid & 63;
    const int fl = lane & 15, qd = lane >> 4;

#pragma unroll
    for (int i = 0; i < 16; ++i)
        async16(&Wlds[(w * 16 + i) * 512], Wimg + (w * 16 + i) * 512 + lane * 8);
    bucket[tid] = 0.0f;
    bucket[tid + 512] = 0.0f;
    if (tid == 0) uctr = 0;
    __syncthreads();

    const float b3v = b3[0];
    float bbv[16], w3v[16];
#pragma unroll
    for (int nt = 0; nt < 16; ++nt) {
        bbv[nt] = b2[nt * 16 + fl];
        w3v[nt] = W3[nt * 16 + fl];
    }

    for (;;) {
        int t = 0;
        if (lane == 0) t = atomicAdd(&uctr, 1);
        t = __shfl(t, 0);
        const int u = blockIdx.x + (t << 8);
        if (u >= NU) break;

        const int ubase = u * 16;
        const int row = ubase + fl;
        const bool valid = row < N_ATOMS;
        const unsigned short* hp = H1 + (size_t)row * 256 + qd * 8;

        short8 h0 = (short8){0, 0, 0, 0, 0, 0, 0, 0};
        if (valid) h0 = *(const short8*)hp;

        float4_t acc[16] = {};
#pragma unroll
        for (int s = 0; s < 8; ++s) {
            short8 hn = (short8){0, 0, 0, 0, 0, 0, 0, 0};
            if (s < 7 && valid) hn = *(const short8*)(hp + (s + 1) * 32);
            const int kc = s * 4 + qd;
#pragma unroll
            for (int nt = 0; nt < 16; ++nt) {
                short8 wf = wfrag(Wlds, nt * 16 + fl, kc);
                acc[nt] = __builtin_amdgcn_mfma_f32_16x16x32_bf16(h0, wf, acc[nt], 0, 0, 0);
            }
            h0 = hn;
        }

        // acc[nt][r]: atom = ubase + qd*4 + r, col = nt*16 + fl
        float rs[4] = {};
#pragma unroll
        for (int nt = 0; nt < 16; ++nt)
#pragma unroll
            for (int r = 0; r < 4; ++r)
                rs[r] += silu(acc[nt][r] + bbv[nt]) * w3v[nt];
#pragma unroll
        for (int r = 0; r < 4; ++r) {
            float v = rs[r];
            v += __shfl_xor(v, 1);
            v += __shfl_xor(v, 2);
            v += __shfl_xor(v, 4);
            v += __shfl_xor(v, 8);
            rs[r] = v;
        }
        if (fl == 0) {
            int atom0 = ubase + qd * 4;
            if (atom0 < N_ATOMS) {   // atom0 % 4 == 0 -> all 4 rows valid
                int4 mb = *(const int4*)&batch[atom0];
                float v0 = rs[0] + b3v, v1 = rs[1] + b3v,
                      v2 = rs[2] + b3v, v3 = rs[3] + b3v;
                if (mb.x == mb.w) {
                    atomicAdd(&bucket[mb.x], (v0 + v1) + (v2 + v3));
                } else {
                    atomicAdd(&bucket[mb.x], v0);
                    atomicAdd(&bucket[mb.y], v1);
                    atomicAdd(&bucket[mb.z], v2);
                    atomicAdd(&bucket[mb.w], v3);
                }
            }
        }
    }
    __syncthreads();
#pragma unroll
    for (int i = 0; i < 2; ++i) {
        int m = tid + i * 512;
        float v = bucket[m];
        if (v != 0.0f) atomicAdd(&out[m], v * SCALE_C);
    }
}

// ---------------------------------------------------------------------------
extern "C" void kernel_launch(void* const* d_in, const int* in_sizes, int n_in,
                              void* d_out, int out_size, void* d_ws, size_t ws_size,
                              hipStream_t stream) {
    const float* A     = (const float*)d_in[0];
    const int*   batch = (const int*)d_in[1];
    const float* W1    = (const float*)d_in[2];
    const float* b1    = (const float*)d_in[3];
    const float* W2    = (const float*)d_in[4];
    const float* b2    = (const float*)d_in[5];
    const float* W3    = (const float*)d_in[6];
    const float* b3    = (const float*)d_in[7];
    float* out = (float*)d_out;

    unsigned short* H1  = (unsigned short*)d_ws;            // 100096*256 bf16
    unsigned short* W1i = H1 + (size_t)100096 * NFEAT;      // 65536 shorts
    unsigned short* W2i = W1i + 65536;                      // 65536 shorts

    prep<<<dim3(512), 256, 0, stream>>>(W1, W2, W1i, W2i, out);
    gemm1<<<dim3(256), 512, 0, stream>>>(A, W1i, b1, H1);
    gemm2<<<dim3(256), 512, 0, stream>>>(H1, W2i, b2, W3, b3, batch, out);
}